// Round 1
// baseline (678.998 us; speedup 1.0000x reference)
//
#include <hip/hip_runtime.h>

typedef __bf16 bf16x8 __attribute__((ext_vector_type(8)));
typedef __bf16 bf16x4 __attribute__((ext_vector_type(4)));
typedef float floatx4 __attribute__((ext_vector_type(4)));

__device__ __forceinline__ __bf16 f2bf(float f) {
  union { float f; unsigned u; } x; x.f = f;
  unsigned r = (x.u + 0x7FFFu + ((x.u >> 16) & 1u)) >> 16;
  union { unsigned short u; __bf16 b; } o; o.u = (unsigned short)r; return o.b;
}
__device__ __forceinline__ float bf2f(__bf16 b) {
  union { unsigned short u; __bf16 b; } i; i.b = b;
  union { unsigned u; float f; } y; y.u = ((unsigned)i.u) << 16; return y.f;
}

#define MFMA16(a, b, c) __builtin_amdgcn_mfma_f32_16x16x32_bf16(a, b, c, 0, 0, 0)

// ---------------- prep: transpose + bf16-convert weights ----------------
__global__ __launch_bounds__(256) void prep_weights(
    const float* __restrict__ W1, const float* __restrict__ WQ,
    const float* __restrict__ WK, const float* __restrict__ WV,
    const float* __restrict__ W2,
    __bf16* __restrict__ w1t, __bf16* __restrict__ wqt,
    __bf16* __restrict__ wkt, __bf16* __restrict__ wvt,
    __bf16* __restrict__ w2t) {
  int i = blockIdx.x * 256 + threadIdx.x;
  if (i < 147456) { int n = i / 768, k = i % 768; w1t[i] = f2bf(W1[k * 192 + n]); return; }
  i -= 147456;
  if (i < 36864) { int n = i / 192, k = i % 192; wqt[i] = f2bf(WQ[k * 192 + n]); return; }
  i -= 36864;
  if (i < 36864) { int n = i / 192, k = i % 192; wkt[i] = f2bf(WK[k * 192 + n]); return; }
  i -= 36864;
  if (i < 36864) { int n = i / 192, k = i % 192; wvt[i] = f2bf(WV[k * 192 + n]); return; }
  i -= 36864;
  if (i < 147456) { int n = i / 192, k = i % 192; w2t[i] = f2bf(W2[k * 768 + n]); return; }
}

// xpos tables: [32][192] each (repeat-2 applied)
__global__ __launch_bounds__(256) void prep_tables(
    float* __restrict__ cq, float* __restrict__ sq,
    float* __restrict__ ck, float* __restrict__ sk) {
  int i = blockIdx.x * 256 + threadIdx.x;
  if (i >= 32 * 96) return;
  int s = i / 96, f = i % 96;
  float base = (2.f * f + 0.4f * 192.f) / (1.4f * 192.f);
  float scale = powf(base, (float)s / 512.f);
  float invf = powf(10000.f, -(float)f / 96.f);
  float ang = (float)s * invf;
  float sn = sinf(ang), cs = cosf(ang);
  int o = s * 192 + 2 * f;
  cq[o] = cs * scale; cq[o + 1] = cs * scale;
  sq[o] = sn * scale; sq[o + 1] = sn * scale;
  ck[o] = cs / scale; ck[o + 1] = cs / scale;
  sk[o] = sn / scale; sk[o + 1] = sn / scale;
}

// Swizzled element offset for stride-192 bf16 tiles: spreads 16 row-strided
// ds_read_b128 lanes across 8 distinct 16B slots (2-way max = free).
#define SW(r, c) ((r) * 192 + ((c) ^ (((r) & 7) << 3)))

// ---------------- main fused kernel: one WG (8 waves) per 32-token sequence ----------------
__global__ __launch_bounds__(512, 6) void retnet_main(
    const float* __restrict__ x, const float* __restrict__ b1,
    const float* __restrict__ b2, const float* __restrict__ ln_g,
    const float* __restrict__ ln_b,
    const __bf16* __restrict__ w1t, const __bf16* __restrict__ wqt,
    const __bf16* __restrict__ wkt, const __bf16* __restrict__ wvt,
    const __bf16* __restrict__ w2t,
    const float* __restrict__ cq, const float* __restrict__ sq,
    const float* __restrict__ ck, const float* __restrict__ sk,
    float* __restrict__ out) {
  // LDS 52224 B -> 3 blocks/CU:
  //   Q   @     0 (12288, swizzled)   [att 32x40 aliases here after phase 4]
  //   K   @ 12288 (12288, swizzled)
  //   Vt  @ 24576 (15360, [d][s] stride 40)
  //   h   @ 39936 (12288, swizzled)   [ret aliases here after phase 4]
  __shared__ __align__(16) char smem[52224];
  __bf16* Q = (__bf16*)smem;
  __bf16* Kl = (__bf16*)(smem + 12288);
  __bf16* Vt = (__bf16*)(smem + 24576);
  __bf16* h = (__bf16*)(smem + 39936);
  __bf16* att = (__bf16*)smem;

  const int tid = threadIdx.x;
  const int wv = tid >> 6;     // 0..7
  const int lane = tid & 63;
  const int l16 = lane & 15;
  const int quad = lane >> 4;
  const int kof = quad * 8;
  const int wm = wv >> 2;      // row half   (0..1)
  const int wn = wv & 3;       // col quarter(0..3)
  const int p = blockIdx.x;
  const float* xblk = x + (size_t)p * 32 * 768;

  // Phase 1: x_down = xr @ W1 + b1 (M=32,N=192,K=768) -> h (swizzled bf16)
  // A-fragments straight from global (fp32 -> bf16 inline); no LDS staging.
  {
    floatx4 acc[3] = {};
    const float* arow = xblk + (wm * 16 + l16) * 768;
#pragma unroll 2
    for (int kk = 0; kk < 768; kk += 32) {
      float4 f0 = *(const float4*)(arow + kk + kof);
      float4 f1 = *(const float4*)(arow + kk + kof + 4);
      bf16x8 a;
      a[0] = f2bf(f0.x); a[1] = f2bf(f0.y); a[2] = f2bf(f0.z); a[3] = f2bf(f0.w);
      a[4] = f2bf(f1.x); a[5] = f2bf(f1.y); a[6] = f2bf(f1.z); a[7] = f2bf(f1.w);
#pragma unroll
      for (int t = 0; t < 3; ++t) {
        bf16x8 bb = *(const bf16x8*)(w1t + (size_t)(wn * 48 + t * 16 + l16) * 768 + kk + kof);
        acc[t] = MFMA16(a, bb, acc[t]);
      }
    }
#pragma unroll
    for (int t = 0; t < 3; ++t) {
      int col = wn * 48 + t * 16 + l16;
      float bias = b1[col];
#pragma unroll
      for (int r = 0; r < 4; ++r) {
        int row = wm * 16 + quad * 4 + r;
        h[SW(row, col)] = f2bf(acc[t][r] + bias);
      }
    }
  }
  __syncthreads();

  // Phase 2: LayerNorm rows of h in place (8 lanes/row; waves 0-3 only,
  // identical arithmetic/order to the verified version).
  if (tid < 256) {
    int r = tid >> 3, g = tid & 7;
    float vals[24]; float s = 0.f, s2 = 0.f;
#pragma unroll
    for (int j = 0; j < 24; ++j) {
      int c = g * 24 + j;
      float v = bf2f(h[SW(r, c)]);
      vals[j] = v; s += v; s2 += v * v;
    }
#pragma unroll
    for (int o = 1; o < 8; o <<= 1) { s += __shfl_xor(s, o); s2 += __shfl_xor(s2, o); }
    float mu = s * (1.f / 192.f);
    float var = s2 * (1.f / 192.f) - mu * mu;
    float rstd = rsqrtf(var + 1e-5f);
#pragma unroll
    for (int j = 0; j < 24; ++j) {
      int c = g * 24 + j;
      h[SW(r, c)] = f2bf((vals[j] - mu) * rstd * ln_g[c] + ln_b[c]);
    }
  }
  __syncthreads();

  // Phase 3: Q/K/V = h @ W (M=32,N=192,K=192); xpos on Q,K; V stored [d][s] stride 40
  auto gemm_h = [&](const __bf16* __restrict__ W, floatx4 (&acc)[3]) {
#pragma unroll
    for (int kk = 0; kk < 192; kk += 32) {
      bf16x8 a = *(const bf16x8*)(h + SW(wm * 16 + l16, kk + kof));
#pragma unroll
      for (int t = 0; t < 3; ++t) {
        bf16x8 bb = *(const bf16x8*)(W + (size_t)(wn * 48 + t * 16 + l16) * 192 + kk + kof);
        acc[t] = MFMA16(a, bb, acc[t]);
      }
    }
  };
  {
    floatx4 acc[3] = {};
    gemm_h(wqt, acc);
#pragma unroll
    for (int t = 0; t < 3; ++t) {
      int col = wn * 48 + t * 16 + l16;
#pragma unroll
      for (int r = 0; r < 4; ++r) {
        int row = wm * 16 + quad * 4 + r;
        float v = acc[t][r];
        float pr = __shfl_xor(v, 1);
        float o = v * cq[row * 192 + col] + ((lane & 1) ? pr : -pr) * sq[row * 192 + col];
        Q[SW(row, col)] = f2bf(o);
      }
    }
  }
  {
    floatx4 acc[3] = {};
    gemm_h(wkt, acc);
#pragma unroll
    for (int t = 0; t < 3; ++t) {
      int col = wn * 48 + t * 16 + l16;
#pragma unroll
      for (int r = 0; r < 4; ++r) {
        int row = wm * 16 + quad * 4 + r;
        float v = acc[t][r];
        float pr = __shfl_xor(v, 1);
        float o = v * ck[row * 192 + col] + ((lane & 1) ? pr : -pr) * sk[row * 192 + col];
        Kl[SW(row, col)] = f2bf(o);
      }
    }
  }
  {
    floatx4 acc[3] = {};
    gemm_h(wvt, acc);
#pragma unroll
    for (int t = 0; t < 3; ++t) {
      int col = wn * 48 + t * 16 + l16;
      bf16x4 pk;
#pragma unroll
      for (int r = 0; r < 4; ++r) pk[r] = f2bf(acc[t][r]);
      *(bf16x4*)(Vt + col * 40 + wm * 16 + quad * 4) = pk;  // [d][s], stride 40
    }
  }
  __syncthreads();

  // Phase 4: att = (Q @ K^T) * decay (32x32); one 16x16 tile per wave (waves 0-3)
  floatx4 acc4 = {0.f, 0.f, 0.f, 0.f};
  const int mt = wv >> 1, nt = wv & 1;
  if (wv < 4) {
#pragma unroll
    for (int kk = 0; kk < 192; kk += 32) {
      bf16x8 a = *(const bf16x8*)(Q + SW(mt * 16 + l16, kk + kof));
      bf16x8 bb = *(const bf16x8*)(Kl + SW(nt * 16 + l16, kk + kof));
      acc4 = MFMA16(a, bb, acc4);
    }
  }
  __syncthreads();  // all Q/K reads done -> att may overwrite Q region
  if (wv < 4) {
#pragma unroll
    for (int r = 0; r < 4; ++r) {
      int i = mt * 16 + quad * 4 + r;
      int j = nt * 16 + l16;
      float v = (i >= j) ? acc4[r] * exp2f((float)(j - i)) : 0.f;
      att[i * 40 + j] = f2bf(v);
    }
  }
  __syncthreads();

  // Phase 5: ret = att @ V (M=32,N=192,K=32) -> ret (aliases h, swizzled)
  {
    floatx4 acc[3] = {};
    bf16x8 a = *(const bf16x8*)(att + (wm * 16 + l16) * 40 + kof);
#pragma unroll
    for (int t = 0; t < 3; ++t) {
      bf16x8 bb = *(const bf16x8*)(Vt + (wn * 48 + t * 16 + l16) * 40 + kof);
      acc[t] = MFMA16(a, bb, acc[t]);
    }
#pragma unroll
    for (int t = 0; t < 3; ++t) {
      int col = wn * 48 + t * 16 + l16;
#pragma unroll
      for (int r = 0; r < 4; ++r) {
        int row = wm * 16 + quad * 4 + r;
        h[SW(row, col)] = f2bf(acc[t][r]);  // ret
      }
    }
  }
  __syncthreads();

  // Phase 6: out = x + ret @ W2 + b2 (M=32,N=768,K=192); each wave owns 16 rows x 192 cols
  {
    bf16x8 af[6];
    const int arow = wm * 16 + l16;
#pragma unroll
    for (int k6 = 0; k6 < 6; ++k6)
      af[k6] = *(const bf16x8*)(h + SW(arow, k6 * 32 + kof));
#pragma unroll
    for (int g = 0; g < 4; ++g) {
      floatx4 acc[3] = {};
#pragma unroll
      for (int k6 = 0; k6 < 6; ++k6) {
#pragma unroll
        for (int t = 0; t < 3; ++t) {
          bf16x8 bb = *(const bf16x8*)(w2t + (size_t)(wn * 192 + g * 48 + t * 16 + l16) * 192 + k6 * 32 + kof);
          acc[t] = MFMA16(af[k6], bb, acc[t]);
        }
      }
#pragma unroll
      for (int t = 0; t < 3; ++t) {
        int col = wn * 192 + g * 48 + t * 16 + l16;
        float bias = b2[col];
#pragma unroll
        for (int r = 0; r < 4; ++r) {
          int row = wm * 16 + quad * 4 + r;
          size_t gi = (size_t)p * 24576 + row * 768 + col;
          out[gi] = xblk[row * 768 + col] + acc[t][r] + bias;
        }
      }
    }
  }
}

extern "C" void kernel_launch(void* const* d_in, const int* in_sizes, int n_in,
                              void* d_out, int out_size, void* d_ws, size_t ws_size,
                              hipStream_t stream) {
  const float* x = (const float*)d_in[0];
  const float* W1 = (const float*)d_in[1];
  const float* b1 = (const float*)d_in[2];
  const float* W2 = (const float*)d_in[3];
  const float* b2 = (const float*)d_in[4];
  const float* lng = (const float*)d_in[5];
  const float* lnb = (const float*)d_in[6];
  const float* WQ = (const float*)d_in[7];
  const float* WK = (const float*)d_in[8];
  const float* WV = (const float*)d_in[9];
  float* out = (float*)d_out;

  char* ws = (char*)d_ws;
  __bf16* w1t = (__bf16*)(ws + 0);
  __bf16* wqt = (__bf16*)(ws + 294912);
  __bf16* wkt = (__bf16*)(ws + 368640);
  __bf16* wvt = (__bf16*)(ws + 442368);
  __bf16* w2t = (__bf16*)(ws + 516096);
  float* cq = (float*)(ws + 811008);
  float* sq = cq + 6144;
  float* ck = sq + 6144;
  float* sk = ck + 6144;

  hipLaunchKernelGGL(prep_weights, dim3(1584), dim3(256), 0, stream,
                     W1, WQ, WK, WV, W2, w1t, wqt, wkt, wvt, w2t);
  hipLaunchKernelGGL(prep_tables, dim3(12), dim3(256), 0, stream, cq, sq, ck, sk);
  hipLaunchKernelGGL(retnet_main, dim3(1568), dim3(512), 0, stream,
                     x, b1, b2, lng, lnb, w1t, wqt, wkt, wvt, w2t, cq, sq, ck, sk, out);
}

// Round 2
// 665.491 us; speedup vs baseline: 1.0203x; 1.0203x over previous
//
#include <hip/hip_runtime.h>

typedef __bf16 bf16x8 __attribute__((ext_vector_type(8)));
typedef __bf16 bf16x4 __attribute__((ext_vector_type(4)));
typedef float floatx4 __attribute__((ext_vector_type(4)));

__device__ __forceinline__ __bf16 f2bf(float f) {
  union { float f; unsigned u; } x; x.f = f;
  unsigned r = (x.u + 0x7FFFu + ((x.u >> 16) & 1u)) >> 16;
  union { unsigned short u; __bf16 b; } o; o.u = (unsigned short)r; return o.b;
}
__device__ __forceinline__ float bf2f(__bf16 b) {
  union { unsigned short u; __bf16 b; } i; i.b = b;
  union { unsigned u; float f; } y; y.u = ((unsigned)i.u) << 16; return y.f;
}

#define MFMA16(a, b, c) __builtin_amdgcn_mfma_f32_16x16x32_bf16(a, b, c, 0, 0, 0)

// ---------------- prep: transpose + bf16-convert weights ----------------
__global__ __launch_bounds__(256) void prep_weights(
    const float* __restrict__ W1, const float* __restrict__ WQ,
    const float* __restrict__ WK, const float* __restrict__ WV,
    const float* __restrict__ W2,
    __bf16* __restrict__ w1t, __bf16* __restrict__ wqt,
    __bf16* __restrict__ wkt, __bf16* __restrict__ wvt,
    __bf16* __restrict__ w2t) {
  int i = blockIdx.x * 256 + threadIdx.x;
  if (i < 147456) { int n = i / 768, k = i % 768; w1t[i] = f2bf(W1[k * 192 + n]); return; }
  i -= 147456;
  if (i < 36864) { int n = i / 192, k = i % 192; wqt[i] = f2bf(WQ[k * 192 + n]); return; }
  i -= 36864;
  if (i < 36864) { int n = i / 192, k = i % 192; wkt[i] = f2bf(WK[k * 192 + n]); return; }
  i -= 36864;
  if (i < 36864) { int n = i / 192, k = i % 192; wvt[i] = f2bf(WV[k * 192 + n]); return; }
  i -= 36864;
  if (i < 147456) { int n = i / 192, k = i % 192; w2t[i] = f2bf(W2[k * 768 + n]); return; }
}

// xpos tables: [32][192] each (repeat-2 applied)
__global__ __launch_bounds__(256) void prep_tables(
    float* __restrict__ cq, float* __restrict__ sq,
    float* __restrict__ ck, float* __restrict__ sk) {
  int i = blockIdx.x * 256 + threadIdx.x;
  if (i >= 32 * 96) return;
  int s = i / 96, f = i % 96;
  float base = (2.f * f + 0.4f * 192.f) / (1.4f * 192.f);
  float scale = powf(base, (float)s / 512.f);
  float invf = powf(10000.f, -(float)f / 96.f);
  float ang = (float)s * invf;
  float sn = sinf(ang), cs = cosf(ang);
  int o = s * 192 + 2 * f;
  cq[o] = cs * scale; cq[o + 1] = cs * scale;
  sq[o] = sn * scale; sq[o + 1] = sn * scale;
  ck[o] = cs / scale; ck[o + 1] = cs / scale;
  sk[o] = sn / scale; sk[o + 1] = sn / scale;
}

// Swizzled element offset for stride-192 bf16 tiles: spreads 16 row-strided
// ds_read_b128 lanes across 8 distinct 16B slots (2-way max = free).
#define SW(r, c) ((r) * 192 + ((c) ^ (((r) & 7) << 3)))

// ---------------- main fused kernel: one WG (8 waves) per 32-token sequence ----------------
// launch_bounds(512,4): VGPR cap 128 — round 1 proved a cap of ~85 (min=6)
// forces catastrophic scratch spill (+130 MB HBM traffic). 2 blocks/CU here.
__global__ __launch_bounds__(512, 4) void retnet_main(
    const float* __restrict__ x, const float* __restrict__ b1,
    const float* __restrict__ b2, const float* __restrict__ ln_g,
    const float* __restrict__ ln_b,
    const __bf16* __restrict__ w1t, const __bf16* __restrict__ wqt,
    const __bf16* __restrict__ wkt, const __bf16* __restrict__ wvt,
    const __bf16* __restrict__ w2t,
    const float* __restrict__ cq, const float* __restrict__ sq,
    const float* __restrict__ ck, const float* __restrict__ sk,
    float* __restrict__ out) {
  // LDS 52224 B:
  //   Q   @     0 (12288, swizzled)   [att 32x40 aliases here after phase 4]
  //   K   @ 12288 (12288, swizzled)
  //   Vt  @ 24576 (15360, [d][s] stride 40)
  //   h   @ 39936 (12288, swizzled)   [ret aliases here after phase 4]
  __shared__ __align__(16) char smem[52224];
  __bf16* Q = (__bf16*)smem;
  __bf16* Kl = (__bf16*)(smem + 12288);
  __bf16* Vt = (__bf16*)(smem + 24576);
  __bf16* h = (__bf16*)(smem + 39936);
  __bf16* att = (__bf16*)smem;

  const int tid = threadIdx.x;
  const int wv = tid >> 6;     // 0..7
  const int lane = tid & 63;
  const int l16 = lane & 15;
  const int quad = lane >> 4;
  const int kof = quad * 8;
  const int wm = wv >> 2;      // row half   (0..1)
  const int wn = wv & 3;       // col quarter(0..3)
  const int p = blockIdx.x;
  const float* xblk = x + (size_t)p * 32 * 768;

  // Phase 1: x_down = xr @ W1 + b1 (M=32,N=192,K=768) -> h (swizzled bf16)
  // A-fragments straight from global (fp32 -> bf16 inline); no LDS staging.
  {
    floatx4 acc[3] = {};
    const float* arow = xblk + (wm * 16 + l16) * 768;
#pragma unroll 2
    for (int kk = 0; kk < 768; kk += 32) {
      float4 f0 = *(const float4*)(arow + kk + kof);
      float4 f1 = *(const float4*)(arow + kk + kof + 4);
      bf16x8 a;
      a[0] = f2bf(f0.x); a[1] = f2bf(f0.y); a[2] = f2bf(f0.z); a[3] = f2bf(f0.w);
      a[4] = f2bf(f1.x); a[5] = f2bf(f1.y); a[6] = f2bf(f1.z); a[7] = f2bf(f1.w);
#pragma unroll
      for (int t = 0; t < 3; ++t) {
        bf16x8 bb = *(const bf16x8*)(w1t + (size_t)(wn * 48 + t * 16 + l16) * 768 + kk + kof);
        acc[t] = MFMA16(a, bb, acc[t]);
      }
    }
#pragma unroll
    for (int t = 0; t < 3; ++t) {
      int col = wn * 48 + t * 16 + l16;
      float bias = b1[col];
#pragma unroll
      for (int r = 0; r < 4; ++r) {
        int row = wm * 16 + quad * 4 + r;
        h[SW(row, col)] = f2bf(acc[t][r] + bias);
      }
    }
  }
  __syncthreads();

  // Phase 2: LayerNorm rows of h in place. All 512 threads: 16 lanes/row,
  // 12 elements each (vals[12] keeps register pressure low).
  {
    int r = tid >> 4, g = tid & 15;
    float vals[12]; float s = 0.f, s2 = 0.f;
#pragma unroll
    for (int j = 0; j < 12; ++j) {
      int c = g * 12 + j;
      float v = bf2f(h[SW(r, c)]);
      vals[j] = v; s += v; s2 += v * v;
    }
#pragma unroll
    for (int o = 1; o < 16; o <<= 1) { s += __shfl_xor(s, o); s2 += __shfl_xor(s2, o); }
    float mu = s * (1.f / 192.f);
    float var = s2 * (1.f / 192.f) - mu * mu;
    float rstd = rsqrtf(var + 1e-5f);
#pragma unroll
    for (int j = 0; j < 12; ++j) {
      int c = g * 12 + j;
      h[SW(r, c)] = f2bf((vals[j] - mu) * rstd * ln_g[c] + ln_b[c]);
    }
  }
  __syncthreads();

  // Phase 3: Q/K/V = h @ W (M=32,N=192,K=192); xpos on Q,K; V stored [d][s] stride 40
  auto gemm_h = [&](const __bf16* __restrict__ W, floatx4 (&acc)[3]) {
#pragma unroll
    for (int kk = 0; kk < 192; kk += 32) {
      bf16x8 a = *(const bf16x8*)(h + SW(wm * 16 + l16, kk + kof));
#pragma unroll
      for (int t = 0; t < 3; ++t) {
        bf16x8 bb = *(const bf16x8*)(W + (size_t)(wn * 48 + t * 16 + l16) * 192 + kk + kof);
        acc[t] = MFMA16(a, bb, acc[t]);
      }
    }
  };
  {
    floatx4 acc[3] = {};
    gemm_h(wqt, acc);
#pragma unroll
    for (int t = 0; t < 3; ++t) {
      int col = wn * 48 + t * 16 + l16;
#pragma unroll
      for (int r = 0; r < 4; ++r) {
        int row = wm * 16 + quad * 4 + r;
        float v = acc[t][r];
        float pr = __shfl_xor(v, 1);
        float o = v * cq[row * 192 + col] + ((lane & 1) ? pr : -pr) * sq[row * 192 + col];
        Q[SW(row, col)] = f2bf(o);
      }
    }
  }
  {
    floatx4 acc[3] = {};
    gemm_h(wkt, acc);
#pragma unroll
    for (int t = 0; t < 3; ++t) {
      int col = wn * 48 + t * 16 + l16;
#pragma unroll
      for (int r = 0; r < 4; ++r) {
        int row = wm * 16 + quad * 4 + r;
        float v = acc[t][r];
        float pr = __shfl_xor(v, 1);
        float o = v * ck[row * 192 + col] + ((lane & 1) ? pr : -pr) * sk[row * 192 + col];
        Kl[SW(row, col)] = f2bf(o);
      }
    }
  }
  {
    floatx4 acc[3] = {};
    gemm_h(wvt, acc);
#pragma unroll
    for (int t = 0; t < 3; ++t) {
      int col = wn * 48 + t * 16 + l16;
      bf16x4 pk;
#pragma unroll
      for (int r = 0; r < 4; ++r) pk[r] = f2bf(acc[t][r]);
      *(bf16x4*)(Vt + col * 40 + wm * 16 + quad * 4) = pk;  // [d][s], stride 40
    }
  }
  __syncthreads();

  // Phase 4: att = (Q @ K^T) * decay (32x32); one 16x16 tile per wave (waves 0-3)
  floatx4 acc4 = {0.f, 0.f, 0.f, 0.f};
  const int mt = wv >> 1, nt = wv & 1;
  if (wv < 4) {
#pragma unroll
    for (int kk = 0; kk < 192; kk += 32) {
      bf16x8 a = *(const bf16x8*)(Q + SW(mt * 16 + l16, kk + kof));
      bf16x8 bb = *(const bf16x8*)(Kl + SW(nt * 16 + l16, kk + kof));
      acc4 = MFMA16(a, bb, acc4);
    }
  }
  __syncthreads();  // all Q/K reads done -> att may overwrite Q region
  if (wv < 4) {
#pragma unroll
    for (int r = 0; r < 4; ++r) {
      int i = mt * 16 + quad * 4 + r;
      int j = nt * 16 + l16;
      float v = (i >= j) ? acc4[r] * exp2f((float)(j - i)) : 0.f;
      att[i * 40 + j] = f2bf(v);
    }
  }
  __syncthreads();

  // Phase 5: ret = att @ V (M=32,N=192,K=32) -> ret (aliases h, swizzled)
  {
    floatx4 acc[3] = {};
    bf16x8 a = *(const bf16x8*)(att + (wm * 16 + l16) * 40 + kof);
#pragma unroll
    for (int t = 0; t < 3; ++t) {
      bf16x8 bb = *(const bf16x8*)(Vt + (wn * 48 + t * 16 + l16) * 40 + kof);
      acc[t] = MFMA16(a, bb, acc[t]);
    }
#pragma unroll
    for (int t = 0; t < 3; ++t) {
      int col = wn * 48 + t * 16 + l16;
#pragma unroll
      for (int r = 0; r < 4; ++r) {
        int row = wm * 16 + quad * 4 + r;
        h[SW(row, col)] = f2bf(acc[t][r]);  // ret
      }
    }
  }
  __syncthreads();

  // Phase 6: out = x + ret @ W2 + b2 (M=32,N=768,K=192); each wave owns 16 rows x 192 cols
  {
    bf16x8 af[6];
    const int arow = wm * 16 + l16;
#pragma unroll
    for (int k6 = 0; k6 < 6; ++k6)
      af[k6] = *(const bf16x8*)(h + SW(arow, k6 * 32 + kof));
#pragma unroll
    for (int g = 0; g < 4; ++g) {
      floatx4 acc[3] = {};
#pragma unroll
      for (int k6 = 0; k6 < 6; ++k6) {
#pragma unroll
        for (int t = 0; t < 3; ++t) {
          bf16x8 bb = *(const bf16x8*)(w2t + (size_t)(wn * 192 + g * 48 + t * 16 + l16) * 192 + k6 * 32 + kof);
          acc[t] = MFMA16(af[k6], bb, acc[t]);
        }
      }
#pragma unroll
      for (int t = 0; t < 3; ++t) {
        int col = wn * 192 + g * 48 + t * 16 + l16;
        float bias = b2[col];
#pragma unroll
        for (int r = 0; r < 4; ++r) {
          int row = wm * 16 + quad * 4 + r;
          size_t gi = (size_t)p * 24576 + row * 768 + col;
          out[gi] = xblk[row * 768 + col] + acc[t][r] + bias;
        }
      }
    }
  }
}

extern "C" void kernel_launch(void* const* d_in, const int* in_sizes, int n_in,
                              void* d_out, int out_size, void* d_ws, size_t ws_size,
                              hipStream_t stream) {
  const float* x = (const float*)d_in[0];
  const float* W1 = (const float*)d_in[1];
  const float* b1 = (const float*)d_in[2];
  const float* W2 = (const float*)d_in[3];
  const float* b2 = (const float*)d_in[4];
  const float* lng = (const float*)d_in[5];
  const float* lnb = (const float*)d_in[6];
  const float* WQ = (const float*)d_in[7];
  const float* WK = (const float*)d_in[8];
  const float* WV = (const float*)d_in[9];
  float* out = (float*)d_out;

  char* ws = (char*)d_ws;
  __bf16* w1t = (__bf16*)(ws + 0);
  __bf16* wqt = (__bf16*)(ws + 294912);
  __bf16* wkt = (__bf16*)(ws + 368640);
  __bf16* wvt = (__bf16*)(ws + 442368);
  __bf16* w2t = (__bf16*)(ws + 516096);
  float* cq = (float*)(ws + 811008);
  float* sq = cq + 6144;
  float* ck = sq + 6144;
  float* sk = ck + 6144;

  hipLaunchKernelGGL(prep_weights, dim3(1584), dim3(256), 0, stream,
                     W1, WQ, WK, WV, W2, w1t, wqt, wkt, wvt, w2t);
  hipLaunchKernelGGL(prep_tables, dim3(12), dim3(256), 0, stream, cq, sq, ck, sk);
  hipLaunchKernelGGL(retnet_main, dim3(1568), dim3(512), 0, stream,
                     x, b1, b2, lng, lnb, w1t, wqt, wkt, wvt, w2t, cq, sq, ck, sk, out);
}

// Round 3
// 452.035 us; speedup vs baseline: 1.5021x; 1.4722x over previous
//
#include <hip/hip_runtime.h>

typedef __bf16 bf16x8 __attribute__((ext_vector_type(8)));
typedef __bf16 bf16x4 __attribute__((ext_vector_type(4)));
typedef float floatx4 __attribute__((ext_vector_type(4)));

__device__ __forceinline__ __bf16 f2bf(float f) {
  union { float f; unsigned u; } x; x.f = f;
  unsigned r = (x.u + 0x7FFFu + ((x.u >> 16) & 1u)) >> 16;
  union { unsigned short u; __bf16 b; } o; o.u = (unsigned short)r; return o.b;
}
__device__ __forceinline__ float bf2f(__bf16 b) {
  union { unsigned short u; __bf16 b; } i; i.b = b;
  union { unsigned u; float f; } y; y.u = ((unsigned)i.u) << 16; return y.f;
}

#define MFMA16(a, b, c) __builtin_amdgcn_mfma_f32_16x16x32_bf16(a, b, c, 0, 0, 0)

// ---------------- prep: weights -> FRAGMENT-MAJOR bf16 layout ----------------
// For each (n-tile, 32-k-step): 64 lanes x 8 elems contiguous (1KB/wave loads).
// Element (nt, kk32, lane, e) = W[k = kk32*32 + (lane>>4)*8 + e][n = nt*16 + (lane&15)].
__global__ __launch_bounds__(256) void prep_weights(
    const float* __restrict__ W1, const float* __restrict__ WQ,
    const float* __restrict__ WK, const float* __restrict__ WV,
    const float* __restrict__ W2,
    __bf16* __restrict__ w1f, __bf16* __restrict__ wqf,
    __bf16* __restrict__ wkf, __bf16* __restrict__ wvf,
    __bf16* __restrict__ w2f) {
  int i = blockIdx.x * 256 + threadIdx.x;
  if (i < 147456) {  // W1: K=768 (kk32 0..23), N=192 (nt 0..11)
    int e = i & 7, lane = (i >> 3) & 63, rest = i >> 9;
    int kk32 = rest % 24, nt = rest / 24;
    int n = nt * 16 + (lane & 15), k = kk32 * 32 + (lane >> 4) * 8 + e;
    w1f[i] = f2bf(W1[k * 192 + n]); return;
  }
  i -= 147456;
  if (i < 36864) {   // WQ: K=192, N=192
    int e = i & 7, lane = (i >> 3) & 63, rest = i >> 9;
    int kk32 = rest % 6, nt = rest / 6;
    int n = nt * 16 + (lane & 15), k = kk32 * 32 + (lane >> 4) * 8 + e;
    wqf[i] = f2bf(WQ[k * 192 + n]); return;
  }
  i -= 36864;
  if (i < 36864) {
    int e = i & 7, lane = (i >> 3) & 63, rest = i >> 9;
    int kk32 = rest % 6, nt = rest / 6;
    int n = nt * 16 + (lane & 15), k = kk32 * 32 + (lane >> 4) * 8 + e;
    wkf[i] = f2bf(WK[k * 192 + n]); return;
  }
  i -= 36864;
  if (i < 36864) {
    int e = i & 7, lane = (i >> 3) & 63, rest = i >> 9;
    int kk32 = rest % 6, nt = rest / 6;
    int n = nt * 16 + (lane & 15), k = kk32 * 32 + (lane >> 4) * 8 + e;
    wvf[i] = f2bf(WV[k * 192 + n]); return;
  }
  i -= 36864;
  if (i < 147456) {  // W2: K=192 (kk32 0..5), N=768 (nt 0..47)
    int e = i & 7, lane = (i >> 3) & 63, rest = i >> 9;
    int kk32 = rest % 6, nt = rest / 6;
    int n = nt * 16 + (lane & 15), k = kk32 * 32 + (lane >> 4) * 8 + e;
    w2f[i] = f2bf(W2[k * 768 + n]); return;
  }
}

// x -> fragment-major bf16: block p, m-tile mt, kk32: 64 lanes x 8 elems contiguous.
// j indexes one lane-fragment: lane=j&63; rest=j>>6; kk32=rest%24; rest2=rest/24 (=p*2+mt).
__global__ __launch_bounds__(256) void prep_xf(
    const float* __restrict__ x, __bf16* __restrict__ xf) {
  int j = blockIdx.x * 256 + threadIdx.x;  // 4,816,896 total
  int lane = j & 63;
  int rest = j >> 6;
  int kk32 = rest % 24;
  int rest2 = rest / 24;                   // p*2 + mt
  size_t row = (size_t)rest2 * 16 + (lane & 15);  // p*32 + mt*16 + l16
  int d = kk32 * 32 + ((lane >> 4) & 3) * 8;
  const float* src = x + row * 768 + d;
  float4 f0 = *(const float4*)(src);
  float4 f1 = *(const float4*)(src + 4);
  bf16x8 a;
  a[0] = f2bf(f0.x); a[1] = f2bf(f0.y); a[2] = f2bf(f0.z); a[3] = f2bf(f0.w);
  a[4] = f2bf(f1.x); a[5] = f2bf(f1.y); a[6] = f2bf(f1.z); a[7] = f2bf(f1.w);
  *(bf16x8*)(xf + (size_t)j * 8) = a;
}

// xpos tables: [32][192] each (repeat-2 applied)
__global__ __launch_bounds__(256) void prep_tables(
    float* __restrict__ cq, float* __restrict__ sq,
    float* __restrict__ ck, float* __restrict__ sk) {
  int i = blockIdx.x * 256 + threadIdx.x;
  if (i >= 32 * 96) return;
  int s = i / 96, f = i % 96;
  float base = (2.f * f + 0.4f * 192.f) / (1.4f * 192.f);
  float scale = powf(base, (float)s / 512.f);
  float invf = powf(10000.f, -(float)f / 96.f);
  float ang = (float)s * invf;
  float sn = sinf(ang), cs = cosf(ang);
  int o = s * 192 + 2 * f;
  cq[o] = cs * scale; cq[o + 1] = cs * scale;
  sq[o] = sn * scale; sq[o + 1] = sn * scale;
  ck[o] = cs / scale; ck[o + 1] = cs / scale;
  sk[o] = sn / scale; sk[o + 1] = sn / scale;
}

// Swizzle for stride-192 bf16 LDS tiles (breaks the 384B-row same-bank pathology).
#define SW(r, c) ((r) * 192 + ((c) ^ (((r) & 7) << 3)))

// ---------------- main fused kernel: one WG (4 waves, 256 thr) per sequence ----------------
// All global loads are coalesced (fragment-major weights + xf). LDS 51200B -> 3 blocks/CU.
template <bool USE_XF>
__global__ __launch_bounds__(256) void retnet_main(
    const float* __restrict__ x, const float* __restrict__ b1,
    const float* __restrict__ b2, const float* __restrict__ ln_g,
    const float* __restrict__ ln_b,
    const __bf16* __restrict__ w1f, const __bf16* __restrict__ wqf,
    const __bf16* __restrict__ wkf, const __bf16* __restrict__ wvf,
    const __bf16* __restrict__ w2f,
    const float* __restrict__ cq, const float* __restrict__ sq,
    const float* __restrict__ ck, const float* __restrict__ sk,
    const __bf16* __restrict__ xf, float* __restrict__ out) {
  // LDS: Q @0 (12288 swz) | K @12288 (12288 swz) | Vt @24576 (12288, [d][s] str32)
  //      att @36864 (2048, str32) | h @38912 (12288 swz; ret aliases after p4)
  __shared__ __align__(16) char smem[51200];
  __bf16* Q = (__bf16*)smem;
  __bf16* Kl = (__bf16*)(smem + 12288);
  __bf16* Vt = (__bf16*)(smem + 24576);
  __bf16* att = (__bf16*)(smem + 36864);
  __bf16* h = (__bf16*)(smem + 38912);

  const int tid = threadIdx.x;
  const int wv = tid >> 6;     // 0..3 (owns 48 cols of d=192)
  const int lane = tid & 63;
  const int l16 = lane & 15;
  const int quad = lane >> 4;
  const int kof = quad * 8;
  const int p = blockIdx.x;
  const float* xblk = x + (size_t)p * 32 * 768;

  // Phase 1: x_down = xr @ W1 + b1 (M=32,N=192,K=768) -> h (swizzled bf16).
  {
    floatx4 acc[2][3] = {};
    if (USE_XF) {
      const __bf16* xfp = xf + (size_t)p * 24576;  // 2 m-tiles * 24 kk * 512
#pragma unroll 4
      for (int kk32 = 0; kk32 < 24; ++kk32) {
        bf16x8 a0 = *(const bf16x8*)(xfp + kk32 * 512 + lane * 8);
        bf16x8 a1 = *(const bf16x8*)(xfp + 12288 + kk32 * 512 + lane * 8);
#pragma unroll
        for (int t = 0; t < 3; ++t) {
          bf16x8 bb = *(const bf16x8*)(w1f + (size_t)((wv * 3 + t) * 24 + kk32) * 512 + lane * 8);
          acc[0][t] = MFMA16(a0, bb, acc[0][t]);
          acc[1][t] = MFMA16(a1, bb, acc[1][t]);
        }
      }
    } else {
      const float* arow0 = xblk + l16 * 768;
      const float* arow1 = xblk + (16 + l16) * 768;
#pragma unroll 2
      for (int kk = 0; kk < 768; kk += 32) {
        float4 f0 = *(const float4*)(arow0 + kk + kof);
        float4 f1 = *(const float4*)(arow0 + kk + kof + 4);
        float4 g0 = *(const float4*)(arow1 + kk + kof);
        float4 g1 = *(const float4*)(arow1 + kk + kof + 4);
        bf16x8 a0, a1;
        a0[0] = f2bf(f0.x); a0[1] = f2bf(f0.y); a0[2] = f2bf(f0.z); a0[3] = f2bf(f0.w);
        a0[4] = f2bf(f1.x); a0[5] = f2bf(f1.y); a0[6] = f2bf(f1.z); a0[7] = f2bf(f1.w);
        a1[0] = f2bf(g0.x); a1[1] = f2bf(g0.y); a1[2] = f2bf(g0.z); a1[3] = f2bf(g0.w);
        a1[4] = f2bf(g1.x); a1[5] = f2bf(g1.y); a1[6] = f2bf(g1.z); a1[7] = f2bf(g1.w);
        int kk32 = kk >> 5;
#pragma unroll
        for (int t = 0; t < 3; ++t) {
          bf16x8 bb = *(const bf16x8*)(w1f + (size_t)((wv * 3 + t) * 24 + kk32) * 512 + lane * 8);
          acc[0][t] = MFMA16(a0, bb, acc[0][t]);
          acc[1][t] = MFMA16(a1, bb, acc[1][t]);
        }
      }
    }
#pragma unroll
    for (int m = 0; m < 2; ++m)
#pragma unroll
      for (int t = 0; t < 3; ++t) {
        int col = wv * 48 + t * 16 + l16;
        float bias = b1[col];
#pragma unroll
        for (int r = 0; r < 4; ++r) {
          int row = m * 16 + quad * 4 + r;
          h[SW(row, col)] = f2bf(acc[m][t][r] + bias);
        }
      }
  }
  __syncthreads();

  // Phase 2: LayerNorm rows of h in place (8 lanes/row, 24 elems each).
  {
    int r = tid >> 3, g = tid & 7;
    float vals[24]; float s = 0.f, s2 = 0.f;
#pragma unroll
    for (int j = 0; j < 24; ++j) {
      int c = g * 24 + j;
      float v = bf2f(h[SW(r, c)]);
      vals[j] = v; s += v; s2 += v * v;
    }
#pragma unroll
    for (int o = 1; o < 8; o <<= 1) { s += __shfl_xor(s, o); s2 += __shfl_xor(s2, o); }
    float mu = s * (1.f / 192.f);
    float var = s2 * (1.f / 192.f) - mu * mu;
    float rstd = rsqrtf(var + 1e-5f);
#pragma unroll
    for (int j = 0; j < 24; ++j) {
      int c = g * 24 + j;
      h[SW(r, c)] = f2bf((vals[j] - mu) * rstd * ln_g[c] + ln_b[c]);
    }
  }
  __syncthreads();

  // Phase 3: Q/K/V = h @ W (M=32,N=192,K=192); xpos on Q,K; V stored [d][s] stride 32.
  auto gemm_h = [&](const __bf16* __restrict__ Wf, floatx4 (&acc)[2][3]) {
#pragma unroll
    for (int kk32 = 0; kk32 < 6; ++kk32) {
      bf16x8 a0 = *(const bf16x8*)(h + SW(l16, kk32 * 32 + kof));
      bf16x8 a1 = *(const bf16x8*)(h + SW(16 + l16, kk32 * 32 + kof));
#pragma unroll
      for (int t = 0; t < 3; ++t) {
        bf16x8 bb = *(const bf16x8*)(Wf + (size_t)((wv * 3 + t) * 6 + kk32) * 512 + lane * 8);
        acc[0][t] = MFMA16(a0, bb, acc[0][t]);
        acc[1][t] = MFMA16(a1, bb, acc[1][t]);
      }
    }
  };
  {
    floatx4 acc[2][3] = {};
    gemm_h(wqf, acc);
#pragma unroll
    for (int m = 0; m < 2; ++m)
#pragma unroll
      for (int t = 0; t < 3; ++t) {
        int col = wv * 48 + t * 16 + l16;
#pragma unroll
        for (int r = 0; r < 4; ++r) {
          int row = m * 16 + quad * 4 + r;
          float v = acc[m][t][r];
          float pr = __shfl_xor(v, 1);
          float o = v * cq[row * 192 + col] + ((lane & 1) ? pr : -pr) * sq[row * 192 + col];
          Q[SW(row, col)] = f2bf(o);
        }
      }
  }
  {
    floatx4 acc[2][3] = {};
    gemm_h(wkf, acc);
#pragma unroll
    for (int m = 0; m < 2; ++m)
#pragma unroll
      for (int t = 0; t < 3; ++t) {
        int col = wv * 48 + t * 16 + l16;
#pragma unroll
        for (int r = 0; r < 4; ++r) {
          int row = m * 16 + quad * 4 + r;
          float v = acc[m][t][r];
          float pr = __shfl_xor(v, 1);
          float o = v * ck[row * 192 + col] + ((lane & 1) ? pr : -pr) * sk[row * 192 + col];
          Kl[SW(row, col)] = f2bf(o);
        }
      }
  }
  {
    floatx4 acc[2][3] = {};
    gemm_h(wvf, acc);
#pragma unroll
    for (int m = 0; m < 2; ++m)
#pragma unroll
      for (int t = 0; t < 3; ++t) {
        int col = wv * 48 + t * 16 + l16;
        bf16x4 pk;
#pragma unroll
        for (int r = 0; r < 4; ++r) pk[r] = f2bf(acc[m][t][r]);
        *(bf16x4*)(Vt + col * 32 + m * 16 + quad * 4) = pk;  // [d][s]
      }
  }
  __syncthreads();

  // Phase 4: att = (Q @ K^T) * decay (32x32); one 16x16 tile per wave.
  {
    int mt = wv >> 1, nt = wv & 1;
    floatx4 acc = {0.f, 0.f, 0.f, 0.f};
#pragma unroll
    for (int kk = 0; kk < 192; kk += 32) {
      bf16x8 a = *(const bf16x8*)(Q + SW(mt * 16 + l16, kk + kof));
      bf16x8 bb = *(const bf16x8*)(Kl + SW(nt * 16 + l16, kk + kof));
      acc = MFMA16(a, bb, acc);
    }
#pragma unroll
    for (int r = 0; r < 4; ++r) {
      int i = mt * 16 + quad * 4 + r;
      int j = nt * 16 + l16;
      float v = (i >= j) ? acc[r] * exp2f((float)(j - i)) : 0.f;
      att[i * 32 + j] = f2bf(v);
    }
  }
  __syncthreads();

  // Phase 5: ret = att @ V (M=32,N=192,K=32) -> ret (aliases h; h dead after p3).
  {
    floatx4 acc[2][3] = {};
    bf16x8 a0 = *(const bf16x8*)(att + l16 * 32 + kof);
    bf16x8 a1 = *(const bf16x8*)(att + (16 + l16) * 32 + kof);
#pragma unroll
    for (int t = 0; t < 3; ++t) {
      bf16x8 bb = *(const bf16x8*)(Vt + (wv * 48 + t * 16 + l16) * 32 + kof);
      acc[0][t] = MFMA16(a0, bb, acc[0][t]);
      acc[1][t] = MFMA16(a1, bb, acc[1][t]);
    }
#pragma unroll
    for (int m = 0; m < 2; ++m)
#pragma unroll
      for (int t = 0; t < 3; ++t) {
        int col = wv * 48 + t * 16 + l16;
#pragma unroll
        for (int r = 0; r < 4; ++r) {
          int row = m * 16 + quad * 4 + r;
          h[SW(row, col)] = f2bf(acc[m][t][r]);  // ret
        }
      }
  }
  __syncthreads();

  // Phase 6: out = x + ret @ W2 + b2 (M=32,N=768,K=192); wave owns 192 cols.
  {
    bf16x8 af[2][6];
#pragma unroll
    for (int k6 = 0; k6 < 6; ++k6) {
      af[0][k6] = *(const bf16x8*)(h + SW(l16, k6 * 32 + kof));
      af[1][k6] = *(const bf16x8*)(h + SW(16 + l16, k6 * 32 + kof));
    }
#pragma unroll
    for (int g = 0; g < 4; ++g) {
      floatx4 acc[2][3] = {};
#pragma unroll
      for (int k6 = 0; k6 < 6; ++k6) {
#pragma unroll
        for (int t = 0; t < 3; ++t) {
          bf16x8 bb = *(const bf16x8*)(w2f + (size_t)((wv * 12 + g * 3 + t) * 6 + k6) * 512 + lane * 8);
          acc[0][t] = MFMA16(af[0][k6], bb, acc[0][t]);
          acc[1][t] = MFMA16(af[1][k6], bb, acc[1][t]);
        }
      }
#pragma unroll
      for (int m = 0; m < 2; ++m)
#pragma unroll
        for (int t = 0; t < 3; ++t) {
          int col = wv * 192 + g * 48 + t * 16 + l16;
          float bias = b2[col];
#pragma unroll
          for (int r = 0; r < 4; ++r) {
            int row = m * 16 + quad * 4 + r;
            size_t gi = (size_t)p * 24576 + row * 768 + col;
            out[gi] = xblk[row * 768 + col] + acc[m][t][r] + bias;
          }
        }
    }
  }
}

extern "C" void kernel_launch(void* const* d_in, const int* in_sizes, int n_in,
                              void* d_out, int out_size, void* d_ws, size_t ws_size,
                              hipStream_t stream) {
  const float* x = (const float*)d_in[0];
  const float* W1 = (const float*)d_in[1];
  const float* b1 = (const float*)d_in[2];
  const float* W2 = (const float*)d_in[3];
  const float* b2 = (const float*)d_in[4];
  const float* lng = (const float*)d_in[5];
  const float* lnb = (const float*)d_in[6];
  const float* WQ = (const float*)d_in[7];
  const float* WK = (const float*)d_in[8];
  const float* WV = (const float*)d_in[9];
  float* out = (float*)d_out;

  char* ws = (char*)d_ws;
  __bf16* w1f = (__bf16*)(ws + 0);
  __bf16* wqf = (__bf16*)(ws + 294912);
  __bf16* wkf = (__bf16*)(ws + 368640);
  __bf16* wvf = (__bf16*)(ws + 442368);
  __bf16* w2f = (__bf16*)(ws + 516096);
  float* cq = (float*)(ws + 811008);
  float* sq = cq + 6144;
  float* ck = sq + 6144;
  float* sk = ck + 6144;
  const size_t xf_off = 909312;                      // 16B-aligned
  const size_t xf_bytes = 77070336;                  // 196*256*768 bf16
  bool use_xf = (ws_size >= xf_off + xf_bytes);
  __bf16* xfp = (__bf16*)(ws + xf_off);

  hipLaunchKernelGGL(prep_weights, dim3(1584), dim3(256), 0, stream,
                     W1, WQ, WK, WV, W2, w1f, wqf, wkf, wvf, w2f);
  hipLaunchKernelGGL(prep_tables, dim3(12), dim3(256), 0, stream, cq, sq, ck, sk);
  if (use_xf) {
    hipLaunchKernelGGL(prep_xf, dim3(18816), dim3(256), 0, stream, x, xfp);
    hipLaunchKernelGGL((retnet_main<true>), dim3(1568), dim3(256), 0, stream,
                       x, b1, b2, lng, lnb, w1f, wqf, wkf, wvf, w2f,
                       cq, sq, ck, sk, (const __bf16*)xfp, out);
  } else {
    hipLaunchKernelGGL((retnet_main<false>), dim3(1568), dim3(256), 0, stream,
                       x, b1, b2, lng, lnb, w1f, wqf, wkf, wvf, w2f,
                       cq, sq, ck, sk, (const __bf16*)nullptr, out);
  }
}